// Round 15
// baseline (69.488 us; speedup 1.0000x reference)
//
#include <hip/hip_runtime.h>

// DivEncLayer — ABLATION ROUND. P3 = r11 kernel verbatim (the real output,
// best-known 28.7us). P0/P1/P2 = phase-truncated clones writing nothing:
//   P0: coalesced staging loop only (loads+cvt+LDS writes+barriers)
//   P1: P0 + ds_read B-frags + 2x MFMA          (acc kept alive via asm)
//   P2: P1 + ELU + sum/ss/dot reduce            (partials kept alive via asm)
//   P3: P2 + shfl combine + epilogue + lout gather + float4 stores -> d_out
// rocprof per-dispatch dur_us gives the marginal cost of each phase.
// Keep-alives (rule: ablation-via-skip DCEs upstream ops) on every truncated
// value; LDS writes are side effects so staging is never DCE'd.

typedef __attribute__((ext_vector_type(8))) short short8;    // 8 bf16
typedef __attribute__((ext_vector_type(16))) float f32x16;

#define XS_STRIDE 40   // shorts per staged row (80 B): b128-aligned
#define KEEP(x) asm volatile("" :: "v"(x))

__device__ __forceinline__ short fbits(__bf16 b) { return __builtin_bit_cast(short, b); }

__device__ __forceinline__ float elu1(float v) {
    return v > 0.f ? v : __expf(v) - 1.f;
}

__device__ __forceinline__ short4 cvt4(float4 v) {
    short4 r;
    r.x = fbits((__bf16)v.x); r.y = fbits((__bf16)v.y);
    r.z = fbits((__bf16)v.z); r.w = fbits((__bf16)v.w);
    return r;
}

template<int PHASE>
__global__ __launch_bounds__(256, 4) void divenc_abl(
    const float* __restrict__ x,      // (16384, 1024)
    const float* __restrict__ W1,     // (128, 8, 32)
    const float* __restrict__ b1,     // (128, 32)
    const float* __restrict__ gamma,  // (128, 32)
    const float* __restrict__ beta,   // (128, 32)
    const float* __restrict__ W2,     // (128, 32)
    const float* __restrict__ b2,     // (128,)
    float* __restrict__ out)          // (16384, 128)  [P<3: unused]
{
    __shared__ short xs[2][64 * XS_STRIDE];   // staged bf16 panels
    __shared__ float lout[256 * 5];           // results, padded stride 5

    const int tid  = threadIdx.x;
    const int w    = tid >> 6;
    const int ln   = tid & 63;
    const int u    = ln & 31;
    const int half = ln >> 5;
    const int qt   = blockIdx.y;      // 0..31
    const int q    = qt * 4 + w;
    const int bx   = blockIdx.x;      // 0..63; band = rows bx*256..+255
    const int band = bx * 256;

    // staging role: 8 threads cover one 128B row; thread t does rows t>>3, +32
    const int srow0 = tid >> 3;
    const int srow1 = srow0 + 32;
    const int schk  = tid & 7;
    const float* xpan = x + qt * 32 + schk * 4;

    // ---- A-frag: lanes<32 = whi (k=0..7), lanes>=32 = wlo (k=8..15) ----
    short8 wfrag;
    #pragma unroll
    for (int j = 0; j < 8; ++j) {
        float f  = W1[q * 256 + j * 32 + u];
        __bf16 h = (__bf16)f;
        wfrag[j] = half ? fbits((__bf16)(f - (float)h)) : fbits(h);
    }

    // ---- params: biasr (MFMA C-in) + g2r in regs, vector loads ----
    f32x16 biasr, g2r;
    float G, C;
    {
        float gs = 0.f, cs = 0.f;
        #pragma unroll
        for (int c = 0; c < 4; ++c) {
            const int ub = q * 32 + 4 * half + 8 * c;
            float4 b1v = *(const float4*)&b1[ub];
            float4 gav = *(const float4*)&gamma[ub];
            float4 w2v = *(const float4*)&W2[ub];
            float4 bev = *(const float4*)&beta[ub];
            #pragma unroll
            for (int j = 0; j < 4; ++j) {
                float g2 = ((const float*)&gav)[j] * ((const float*)&w2v)[j];
                biasr[4 * c + j] = ((const float*)&b1v)[j];
                g2r[4 * c + j]   = g2;
                gs += g2;
                cs += ((const float*)&bev)[j] * ((const float*)&w2v)[j];
            }
        }
        gs += __shfl_xor(gs, 32);
        cs += __shfl_xor(cs, 32);
        G = gs;
        C = cs + b2[q];
    }

    // ---- prologue: stage iter-0 panel (fully coalesced) ----
    {
        float4 g0 = *(const float4*)(xpan + (size_t)(band + srow0) * 1024);
        float4 g1 = *(const float4*)(xpan + (size_t)(band + srow1) * 1024);
        *(short4*)&xs[0][srow0 * XS_STRIDE + schk * 4] = cvt4(g0);
        *(short4*)&xs[0][srow1 * XS_STRIDE + schk * 4] = cvt4(g1);
    }
    __syncthreads();

    #pragma unroll 1
    for (int it = 0; it < 4; ++it) {
        const int cur = it & 1;
        const int b0  = it * 64;        // row offset within band

        // issue next panel's coalesced loads early
        float4 g0, g1;
        if (it < 3) {
            g0 = *(const float4*)(xpan + (size_t)(band + b0 + 64 + srow0) * 1024);
            g1 = *(const float4*)(xpan + (size_t)(band + b0 + 64 + srow1) * 1024);
        }

        if constexpr (PHASE >= 1) {
            // B-frags from staged panel (one b128 each, halves broadcast-dup)
            short8 xa = *(const short8*)&xs[cur][u * XS_STRIDE + w * 8];
            short8 xb = *(const short8*)&xs[cur][(u + 32) * XS_STRIDE + w * 8];

            f32x16 accA = __builtin_amdgcn_mfma_f32_32x32x16_bf16(wfrag, xa, biasr, 0, 0, 0);
            f32x16 accB = __builtin_amdgcn_mfma_f32_32x32x16_bf16(wfrag, xb, biasr, 0, 0, 0);

            if constexpr (PHASE == 1) {
                KEEP(accA[0]); KEEP(accA[15]);
                KEEP(accB[0]); KEEP(accB[15]);
            }

            if constexpr (PHASE >= 2) {
                // tile A
                {
                    float sum = 0.f, ss = 0.f, dot = 0.f;
                    #pragma unroll
                    for (int r = 0; r < 16; ++r) {
                        float e = elu1(accA[r]);
                        sum += e;
                        ss  = fmaf(e, e, ss);
                        dot = fmaf(e, g2r[r], dot);
                    }
                    if constexpr (PHASE == 2) {
                        KEEP(sum); KEEP(ss); KEEP(dot);
                    } else {
                        sum += __shfl_xor(sum, 32);
                        ss  += __shfl_xor(ss, 32);
                        dot += __shfl_xor(dot, 32);
                        float mu  = sum * 0.03125f;
                        float var = fmaf(-mu, mu, ss * 0.03125f);
                        float inv = rsqrtf(var + 1e-3f);
                        float res = fmaf(inv, fmaf(-mu, G, dot), C);
                        if (half == 0) lout[(b0 + u) * 5 + w] = res;
                    }
                }
                // tile B
                {
                    float sum = 0.f, ss = 0.f, dot = 0.f;
                    #pragma unroll
                    for (int r = 0; r < 16; ++r) {
                        float e = elu1(accB[r]);
                        sum += e;
                        ss  = fmaf(e, e, ss);
                        dot = fmaf(e, g2r[r], dot);
                    }
                    if constexpr (PHASE == 2) {
                        KEEP(sum); KEEP(ss); KEEP(dot);
                    } else {
                        sum += __shfl_xor(sum, 32);
                        ss  += __shfl_xor(ss, 32);
                        dot += __shfl_xor(dot, 32);
                        float mu  = sum * 0.03125f;
                        float var = fmaf(-mu, mu, ss * 0.03125f);
                        float inv = rsqrtf(var + 1e-3f);
                        float res = fmaf(inv, fmaf(-mu, G, dot), C);
                        if (half == 0) lout[(b0 + 32 + u) * 5 + w] = res;
                    }
                }
            }
        } else {
            KEEP(wfrag[0]);   // keep setup comparable across phases
        }

        // write next panel, then the iter barrier (identical in all phases)
        if (it < 3) {
            *(short4*)&xs[cur ^ 1][srow0 * XS_STRIDE + schk * 4] = cvt4(g0);
            *(short4*)&xs[cur ^ 1][srow1 * XS_STRIDE + schk * 4] = cvt4(g1);
        }
        __syncthreads();
    }

    if constexpr (PHASE >= 3) {
        // ---- gather/store: 256 rows, one float4 per thread ----
        float4 o;
        o.x = lout[tid * 5 + 0];
        o.y = lout[tid * 5 + 1];
        o.z = lout[tid * 5 + 2];
        o.w = lout[tid * 5 + 3];
        *(float4*)(out + (size_t)(band + tid) * 128 + qt * 4) = o;
    }
}

extern "C" void kernel_launch(void* const* d_in, const int* in_sizes, int n_in,
                              void* d_out, int out_size, void* d_ws, size_t ws_size,
                              hipStream_t stream) {
    const float* x     = (const float*)d_in[0];
    const float* W1    = (const float*)d_in[1];
    const float* b1    = (const float*)d_in[2];
    const float* gamma = (const float*)d_in[3];
    const float* beta  = (const float*)d_in[4];
    const float* W2    = (const float*)d_in[5];
    const float* b2    = (const float*)d_in[6];
    float* out = (float*)d_out;
    float* ws  = (float*)d_ws;   // dummy target for truncated variants

    dim3 grid(64, 32);   // (256-row bands, q-tiles of 4) = 2048 blocks

    // P3 first: the real kernel (writes d_out; r11 structure verbatim)
    divenc_abl<3><<<grid, 256, 0, stream>>>(x, W1, b1, gamma, beta, W2, b2, out);
    // Ablation probes (write nothing; keep-alives prevent DCE)
    divenc_abl<0><<<grid, 256, 0, stream>>>(x, W1, b1, gamma, beta, W2, b2, ws);
    divenc_abl<1><<<grid, 256, 0, stream>>>(x, W1, b1, gamma, beta, W2, b2, ws);
    divenc_abl<2><<<grid, 256, 0, stream>>>(x, W1, b1, gamma, beta, W2, b2, ws);
}